// Round 3
// baseline (1710.755 us; speedup 1.0000x reference)
//
#include <hip/hip_runtime.h>
#include <stdint.h>

// Problem constants
#define BATCH 16
#define CIN   1024
#define HWSZ  1024          // H*W
#define NPOS  16384         // BATCH * HWSZ
#define DCODE 1024
#define KCB   2048

// d_out is FLOAT32: [0,16777216) quant_st (B,D,H,W); [16777216] diff; [16777217,+16384) indices
#define OUT_QUANT 0
#define OUT_DIFF  16777216
#define OUT_IDX   16777217

// ws layout (bytes) -- small structures FIRST, chunked xp after.
#define PACKED_OFF 0u                                  // 16384 u64 = 128 KB
#define CNORM_OFF  (NPOS * 8u)                         // 2048 f32 = 8 KB
#define DIFF_OFF   (CNORM_OFF + KCB * 4u)              // 1 double
#define XP_OFF     (256u * 1024u)                      // chunked XP: DCODE*NC*4 bytes

__global__ void k_init(unsigned long long* __restrict__ packed,
                       double* __restrict__ diffsum) {
  int i = blockIdx.x * 256 + threadIdx.x;
  if (i < NPOS) packed[i] = 0xFFFFFFFFFFFFFFFFull;
  if (i == 0) *diffsum = 0.0;
}

// cnorm[k] = sum_d codebook[d][k]^2  (double accumulation for argmin robustness)
__global__ void k_cnorm(const float* __restrict__ cb, float* __restrict__ cnorm) {
  int k = blockIdx.x * 256 + threadIdx.x;
  if (k >= KCB) return;
  double s = 0.0;
  for (int d = 0; d < DCODE; ++d) { float v = cb[(size_t)d * KCB + k]; s += (double)v * v; }
  cnorm[k] = (float)s;
}

// GEMM1 (chunked over n): XP[d][n-n_base] = sum_c conv_w[d][c] * x[b][c][hw] + bias[d]
// 128x128 tile, BK=8, 256 threads, 8x8 microtile. xp chunk stored (D, NC).
__global__ __launch_bounds__(256) void k_gemm1(const float* __restrict__ x,
                                               const float* __restrict__ w,
                                               const float* __restrict__ bias,
                                               float* __restrict__ xp,
                                               int n_base, int NC) {
  __shared__ float As[8][132]; // [c][d]
  __shared__ float Bs[8][132]; // [c][n]
  const int tid = threadIdx.x;
  const int tx = tid & 15, ty = tid >> 4;
  const int nloc0 = blockIdx.x * 128;        // local n within chunk
  const int n0 = n_base + nloc0;             // global n
  const int d0 = blockIdx.y * 128;
  const int b = n0 >> 10;
  const int hw0 = n0 & 1023;
  const float* xb = x + (size_t)b * CIN * HWSZ + hw0;

  const int a_d = tid >> 1, a_c = (tid & 1) * 4;   // A: 128 d rows x 8 c
  const int b_c = tid >> 5, b_n = (tid & 31) * 4;  // B: 8 c rows x 128 n

  float acc[8][8];
  #pragma unroll
  for (int i = 0; i < 8; ++i)
    #pragma unroll
    for (int j = 0; j < 8; ++j) acc[i][j] = 0.f;

  for (int c0 = 0; c0 < CIN; c0 += 8) {
    float4 av = *(const float4*)&w[(size_t)(d0 + a_d) * CIN + c0 + a_c];
    float4 bv = *(const float4*)&xb[(size_t)(c0 + b_c) * HWSZ + b_n];
    __syncthreads();
    As[a_c + 0][a_d] = av.x; As[a_c + 1][a_d] = av.y;
    As[a_c + 2][a_d] = av.z; As[a_c + 3][a_d] = av.w;
    *(float4*)&Bs[b_c][b_n] = bv;
    __syncthreads();
    #pragma unroll
    for (int k = 0; k < 8; ++k) {
      float a[8], bb[8];
      *(float4*)&a[0]  = *(const float4*)&As[k][ty * 8];
      *(float4*)&a[4]  = *(const float4*)&As[k][ty * 8 + 4];
      *(float4*)&bb[0] = *(const float4*)&Bs[k][tx * 8];
      *(float4*)&bb[4] = *(const float4*)&Bs[k][tx * 8 + 4];
      #pragma unroll
      for (int i = 0; i < 8; ++i)
        #pragma unroll
        for (int j = 0; j < 8; ++j) acc[i][j] = fmaf(a[i], bb[j], acc[i][j]);
    }
  }
  #pragma unroll
  for (int i = 0; i < 8; ++i) {
    const int d = d0 + ty * 8 + i;
    const float bi = bias[d];
    float4 v0, v1;
    v0.x = acc[i][0] + bi; v0.y = acc[i][1] + bi; v0.z = acc[i][2] + bi; v0.w = acc[i][3] + bi;
    v1.x = acc[i][4] + bi; v1.y = acc[i][5] + bi; v1.z = acc[i][6] + bi; v1.w = acc[i][7] + bi;
    *(float4*)&xp[(size_t)d * NC + nloc0 + tx * 8]     = v0;
    *(float4*)&xp[(size_t)d * NC + nloc0 + tx * 8 + 4] = v1;
  }
}

// GEMM2 fused with argmin (chunked): S[n][k] = sum_d XP[d][n]*cb[d][k];
// v = cnorm[k] - 2S (monotone in true dist); per-row global argmin via packed u64 atomicMin.
__global__ __launch_bounds__(256) void k_gemm2(const float* __restrict__ xp,
                                               const float* __restrict__ cb,
                                               const float* __restrict__ cnorm,
                                               unsigned long long* __restrict__ packed,
                                               int n_base, int NC) {
  __shared__ float As[8][132]; // [d][n]
  __shared__ float Bs[8][132]; // [d][k]
  const int tid = threadIdx.x;
  const int tx = tid & 15, ty = tid >> 4;
  const int k0 = blockIdx.x * 128;      // 16 tiles of codes
  const int nloc0 = blockIdx.y * 128;   // local n tile
  const int l_r = tid >> 5, l_c = (tid & 31) * 4;

  float acc[8][8];
  #pragma unroll
  for (int i = 0; i < 8; ++i)
    #pragma unroll
    for (int j = 0; j < 8; ++j) acc[i][j] = 0.f;

  for (int d0 = 0; d0 < DCODE; d0 += 8) {
    float4 av = *(const float4*)&xp[(size_t)(d0 + l_r) * NC + nloc0 + l_c];
    float4 bv = *(const float4*)&cb[(size_t)(d0 + l_r) * KCB + k0 + l_c];
    __syncthreads();
    *(float4*)&As[l_r][l_c] = av;
    *(float4*)&Bs[l_r][l_c] = bv;
    __syncthreads();
    #pragma unroll
    for (int k = 0; k < 8; ++k) {
      float a[8], bb[8];
      *(float4*)&a[0]  = *(const float4*)&As[k][ty * 8];
      *(float4*)&a[4]  = *(const float4*)&As[k][ty * 8 + 4];
      *(float4*)&bb[0] = *(const float4*)&Bs[k][tx * 8];
      *(float4*)&bb[4] = *(const float4*)&Bs[k][tx * 8 + 4];
      #pragma unroll
      for (int i = 0; i < 8; ++i)
        #pragma unroll
        for (int j = 0; j < 8; ++j) acc[i][j] = fmaf(a[i], bb[j], acc[i][j]);
    }
  }
  // per-row argmin over this block's 128 codes, then global merge
  #pragma unroll
  for (int i = 0; i < 8; ++i) {
    float best = 3.4e38f; int bidx = 0;
    #pragma unroll
    for (int j = 0; j < 8; ++j) {
      const int kk = k0 + tx * 8 + j;
      const float v = cnorm[kk] - 2.0f * acc[i][j];
      if (v < best) { best = v; bidx = kk; }   // keeps smallest kk on ties
    }
    union { float f; uint32_t u; } cv; cv.f = best;
    uint32_t hi = cv.u ^ ((uint32_t)((int32_t)cv.u >> 31) | 0x80000000u); // order-preserving
    unsigned long long key = ((unsigned long long)hi << 32) | (uint32_t)bidx;
    #pragma unroll
    for (int s = 1; s < 16; s <<= 1) {
      unsigned long long o = __shfl_xor(key, s, 64);
      if (o < key) key = o;
    }
    if (tx == 0) atomicMin(&packed[n_base + nloc0 + ty * 8 + i], key);
  }
}

// Gather quantized vectors (chunked), write quant_st (f32), accumulate sum((q - xp)^2)
// grid: (NC/1024, 1024): x = which b-slab of the chunk, y = d
__global__ __launch_bounds__(256) void k_gather(const float* __restrict__ cb,
                                                const float* __restrict__ xp,
                                                const unsigned long long* __restrict__ packed,
                                                float* __restrict__ out,
                                                double* __restrict__ diffsum,
                                                int n_base, int NC) {
  const int d = blockIdx.y;
  const int n0 = n_base + blockIdx.x * 1024;   // global n, multiple of 1024
  const int b = n0 >> 10;
  const int tid = threadIdx.x;
  const float* cbrow = cb + (size_t)d * KCB;
  const float* xprow = xp + (size_t)d * NC + (n0 - n_base);
  const unsigned long long* prow = packed + n0;
  float* orow = out + OUT_QUANT + (size_t)b * DCODE * HWSZ + (size_t)d * HWSZ;
  float local = 0.f;
  #pragma unroll
  for (int it = 0; it < 4; ++it) {
    const int hw = it * 256 + tid;
    uint32_t idx = (uint32_t)(prow[hw] & 0xFFFFFFFFu);
    if (idx > (KCB - 1)) idx = KCB - 1;   // defensive clamp
    const float q = cbrow[idx];
    const float xv = xprow[hw];
    const float dd = q - xv;
    local += dd * dd;
    orow[hw] = q;
  }
  __shared__ float red[256];
  red[tid] = local;
  __syncthreads();
  for (int s = 128; s > 0; s >>= 1) {
    if (tid < s) red[tid] += red[tid + s];
    __syncthreads();
  }
  if (tid == 0) atomicAdd(diffsum, (double)red[0]);
}

__global__ void k_final(const unsigned long long* __restrict__ packed,
                        const double* __restrict__ diffsum,
                        float* __restrict__ out) {
  int i = blockIdx.x * 256 + threadIdx.x;
  if (i < NPOS) {
    uint32_t idx = (uint32_t)(packed[i] & 0xFFFFFFFFu);
    if (idx > (KCB - 1)) idx = KCB - 1;
    out[OUT_IDX + i] = (float)idx;          // indices as exact f32 integers
  }
  if (i == 0) out[OUT_DIFF] = (float)(*diffsum / ((double)NPOS * (double)DCODE));
}

extern "C" void kernel_launch(void* const* d_in, const int* in_sizes, int n_in,
                              void* d_out, int out_size, void* d_ws, size_t ws_size,
                              hipStream_t stream) {
  const float* x    = (const float*)d_in[0];
  const float* w    = (const float*)d_in[1];
  const float* bias = (const float*)d_in[2];
  const float* cb   = (const float*)d_in[3];
  float* out = (float*)d_out;
  char* ws = (char*)d_ws;
  unsigned long long* packed = (unsigned long long*)(ws + PACKED_OFF);
  float* cnorm = (float*)(ws + CNORM_OFF);
  double* diffsum = (double*)(ws + DIFF_OFF);
  float* xp = (float*)(ws + XP_OFF);

  // Choose chunk size NC honestly from ws_size. Footprint = XP_OFF + DCODE*NC*4.
  int NC = 1024;
  if (ws_size >= (size_t)XP_OFF + (size_t)DCODE * 4096 * 4) NC = 4096;
  else if (ws_size >= (size_t)XP_OFF + (size_t)DCODE * 2048 * 4) NC = 2048;
  const int nchunks = NPOS / NC;

  k_init<<<64, 256, 0, stream>>>(packed, diffsum);
  k_cnorm<<<8, 256, 0, stream>>>(cb, cnorm);
  for (int c = 0; c < nchunks; ++c) {
    const int n_base = c * NC;
    k_gemm1<<<dim3(NC / 128, 8), 256, 0, stream>>>(x, w, bias, xp, n_base, NC);
    k_gemm2<<<dim3(KCB / 128, NC / 128), 256, 0, stream>>>(xp, cb, cnorm, packed, n_base, NC);
    k_gather<<<dim3(NC / 1024, DCODE), 256, 0, stream>>>(cb, xp, packed, out, diffsum, n_base, NC);
  }
  k_final<<<64, 256, 0, stream>>>(packed, diffsum, out);
}

// Round 4
// 1269.205 us; speedup vs baseline: 1.3479x; 1.3479x over previous
//
#include <hip/hip_runtime.h>
#include <stdint.h>

// Problem constants
#define BATCH 16
#define CIN   1024
#define HWSZ  1024
#define NPOS  16384
#define DCODE 1024
#define KCB   2048

// d_out FLOAT32: [0,16777216) quant (B,D,H,W); [16777216] diff; [16777217,+16384) indices
#define OUT_QUANT 0
#define OUT_DIFF  16777216
#define OUT_IDX   16777217

// ws layout (bytes)
#define OFF_PACKED 0u            // 16384 u64 = 128 KB
#define OFF_CNORM  131072u       // 2048 f32
#define OFF_DIFF   139264u       // 1 double
#define OFF_WH     262144u       // [d][c] f16, 2 MB
#define OFF_WL     2359296u
#define OFF_CBH    4456448u      // [k][d] f16, 4 MB
#define OFF_CBL    8650752u
#define OFF_DYN    12845056u
// dynamic region per chunk: xp f32 [D][NC] (NC*4096 B) | xh [NC][C] (NC*2048) | xl (NC*2048)
//                           | xph [NC][D] (NC*2048) | xpl (NC*2048)  => NC*12288 total + xh/xl extra
// full per-chunk: NC*4096 + 4*NC*2048 = NC*12288? xp(4096)+xh(2048)+xl(2048)+xph(2048)+xpl(2048)=NC*12288. Yes.

typedef _Float16 f16x8 __attribute__((ext_vector_type(8)));
typedef float f32x4 __attribute__((ext_vector_type(4)));
union H4 { _Float16 h[4]; uint2 u; };
union H8 { _Float16 h[8]; uint4 u; };

__device__ __forceinline__ void gl_lds16(const void* g, void* l) {
  __builtin_amdgcn_global_load_lds(
      (const __attribute__((address_space(1))) uint32_t*)g,
      (__attribute__((address_space(3))) uint32_t*)l, 16, 0, 0);
}

__global__ void k_init(unsigned long long* __restrict__ packed, double* __restrict__ diffsum) {
  int i = blockIdx.x * 256 + threadIdx.x;
  if (i < NPOS) packed[i] = 0xFFFFFFFFFFFFFFFFull;
  if (i == 0) *diffsum = 0.0;
}

__global__ __launch_bounds__(256) void k_prep_w(const float* __restrict__ w,
                                                _Float16* __restrict__ wh, _Float16* __restrict__ wl) {
  const int d = blockIdx.x;
  const int c = threadIdx.x * 4;
  float4 v = *(const float4*)&w[(size_t)d * CIN + c];
  H4 hh, ll;
  float vv[4] = {v.x, v.y, v.z, v.w};
  #pragma unroll
  for (int i = 0; i < 4; ++i) {
    _Float16 h = (_Float16)vv[i];
    hh.h[i] = h;
    ll.h[i] = (_Float16)(vv[i] - (float)h);
  }
  *(uint2*)&wh[(size_t)d * CIN + c] = hh.u;
  *(uint2*)&wl[(size_t)d * CIN + c] = ll.u;
}

// cbh/cbl [k][d] from cb [d][k]: tiled 64x64 transpose + split
__global__ __launch_bounds__(256) void k_prep_cb(const float* __restrict__ cb,
                                                 _Float16* __restrict__ cbh, _Float16* __restrict__ cbl) {
  __shared__ float ts[64][65];
  const int t = threadIdx.x;
  const int k0 = blockIdx.x * 64, d0 = blockIdx.y * 64;
  #pragma unroll
  for (int i = 0; i < 4; ++i) {
    const int r = i * 16 + (t >> 4);          // d-local
    float4 v = *(const float4*)&cb[(size_t)(d0 + r) * KCB + k0 + (t & 15) * 4];
    ts[r][(t & 15) * 4 + 0] = v.x; ts[r][(t & 15) * 4 + 1] = v.y;
    ts[r][(t & 15) * 4 + 2] = v.z; ts[r][(t & 15) * 4 + 3] = v.w;
  }
  __syncthreads();
  const int j = t >> 2;          // k-local
  const int q = t & 3;           // d quarter
  H8 hh[2], ll[2];
  #pragma unroll
  for (int e = 0; e < 16; ++e) {
    float xv = ts[q * 16 + e][j];
    _Float16 h = (_Float16)xv;
    hh[e >> 3].h[e & 7] = h;
    ll[e >> 3].h[e & 7] = (_Float16)(xv - (float)h);
  }
  size_t o = (size_t)(k0 + j) * DCODE + d0 + q * 16;
  *(uint4*)&cbh[o] = hh[0].u; *(uint4*)&cbh[o + 8] = hh[1].u;
  *(uint4*)&cbl[o] = ll[0].u; *(uint4*)&cbl[o + 8] = ll[1].u;
}

// xh/xl [nloc][c] from x[b][c][hw] for this chunk
__global__ __launch_bounds__(256) void k_prep_x(const float* __restrict__ x,
                                                _Float16* __restrict__ xh, _Float16* __restrict__ xl,
                                                int n_base) {
  __shared__ float ts[64][65];
  const int t = threadIdx.x;
  const int nt0 = blockIdx.x * 64;
  const int c0 = blockIdx.y * 64;
  const int ng = n_base + nt0;
  const int b = ng >> 10, hw0 = ng & 1023;
  #pragma unroll
  for (int i = 0; i < 4; ++i) {
    const int r = i * 16 + (t >> 4);          // c-local
    float4 v = *(const float4*)&x[((size_t)b * CIN + c0 + r) * HWSZ + hw0 + (t & 15) * 4];
    ts[r][(t & 15) * 4 + 0] = v.x; ts[r][(t & 15) * 4 + 1] = v.y;
    ts[r][(t & 15) * 4 + 2] = v.z; ts[r][(t & 15) * 4 + 3] = v.w;
  }
  __syncthreads();
  const int j = t >> 2;          // n-local
  const int q = t & 3;           // c quarter
  H8 hh[2], ll[2];
  #pragma unroll
  for (int e = 0; e < 16; ++e) {
    float xv = ts[q * 16 + e][j];
    _Float16 h = (_Float16)xv;
    hh[e >> 3].h[e & 7] = h;
    ll[e >> 3].h[e & 7] = (_Float16)(xv - (float)h);
  }
  size_t o = (size_t)(nt0 + j) * CIN + c0 + q * 16;
  *(uint4*)&xh[o] = hh[0].u; *(uint4*)&xh[o + 8] = hh[1].u;
  *(uint4*)&xl[o] = ll[0].u; *(uint4*)&xl[o + 8] = ll[1].u;
}

__global__ __launch_bounds__(256) void k_cnorm2(const _Float16* __restrict__ cbh,
                                                const _Float16* __restrict__ cbl,
                                                float* __restrict__ cnorm) {
  __shared__ double rd[256];
  const int k = blockIdx.x;
  const int t = threadIdx.x;
  H4 hh, ll;
  hh.u = *(const uint2*)&cbh[(size_t)k * DCODE + t * 4];
  ll.u = *(const uint2*)&cbl[(size_t)k * DCODE + t * 4];
  double s = 0.0;
  #pragma unroll
  for (int i = 0; i < 4; ++i) {
    float v = (float)hh.h[i] + (float)ll.h[i];
    s += (double)v * v;
  }
  rd[t] = s;
  __syncthreads();
  for (int st = 128; st > 0; st >>= 1) {
    if (t < st) rd[t] += rd[t + st];
    __syncthreads();
  }
  if (t == 0) cnorm[k] = (float)rd[0];
}

// ---- MFMA GEMM1: C[d][n] = W[d][c] x X^T[c][n] + bias ----
__global__ __launch_bounds__(256) void k_gemm1_mfma(
    const _Float16* __restrict__ wh, const _Float16* __restrict__ wl,
    const _Float16* __restrict__ xh, const _Float16* __restrict__ xl,
    const float* __restrict__ bias, float* __restrict__ xp,
    _Float16* __restrict__ xph, _Float16* __restrict__ xpl, int NC) {
  __shared__ __align__(16) _Float16 As[128 * 64];
  __shared__ __align__(16) _Float16 Bs[128 * 64];
  const int tid = threadIdx.x;
  const int lane = tid & 63, wid = tid >> 6;
  const int wm = wid >> 1, wn = wid & 1;
  const int nloc0 = blockIdx.x * 128;
  const int d0 = blockIdx.y * 128;
  const int r_off = lane >> 3, c16 = lane & 7;

  f32x4 acc[4][4];
  #pragma unroll
  for (int i = 0; i < 4; ++i)
    #pragma unroll
    for (int j = 0; j < 4; ++j) acc[i][j] = (f32x4){0.f, 0.f, 0.f, 0.f};

  for (int kt = 0; kt < CIN / 32; ++kt) {
    const int dk = kt * 32;
    #pragma unroll
    for (int j = 0; j < 4; ++j) {
      const int r = wid * 32 + j * 8 + r_off;
      const int lg = c16 ^ (r & 7);
      const _Float16* srcA = (lg < 4 ? wh : wl) + (size_t)(d0 + r) * CIN + dk + (lg & 3) * 8;
      gl_lds16(srcA, As + (size_t)(wid * 32 + j * 8) * 64);
      const _Float16* srcB = (lg < 4 ? xh : xl) + (size_t)(nloc0 + r) * CIN + dk + (lg & 3) * 8;
      gl_lds16(srcB, Bs + (size_t)(wid * 32 + j * 8) * 64);
    }
    __syncthreads();
    f16x8 a_h[4], a_l[4], b_h[4], b_l[4];
    const int kg = lane >> 4;
    #pragma unroll
    for (int mi = 0; mi < 4; ++mi) {
      const int r = wm * 64 + mi * 16 + (lane & 15);
      a_h[mi] = *(const f16x8*)&As[r * 64 + ((kg)     ^ (r & 7)) * 8];
      a_l[mi] = *(const f16x8*)&As[r * 64 + ((kg + 4) ^ (r & 7)) * 8];
    }
    #pragma unroll
    for (int ni = 0; ni < 4; ++ni) {
      const int r = wn * 64 + ni * 16 + (lane & 15);
      b_h[ni] = *(const f16x8*)&Bs[r * 64 + ((kg)     ^ (r & 7)) * 8];
      b_l[ni] = *(const f16x8*)&Bs[r * 64 + ((kg + 4) ^ (r & 7)) * 8];
    }
    #pragma unroll
    for (int mi = 0; mi < 4; ++mi)
      #pragma unroll
      for (int ni = 0; ni < 4; ++ni) {
        acc[mi][ni] = __builtin_amdgcn_mfma_f32_16x16x32_f16(a_h[mi], b_h[ni], acc[mi][ni], 0, 0, 0);
        acc[mi][ni] = __builtin_amdgcn_mfma_f32_16x16x32_f16(a_h[mi], b_l[ni], acc[mi][ni], 0, 0, 0);
        acc[mi][ni] = __builtin_amdgcn_mfma_f32_16x16x32_f16(a_l[mi], b_h[ni], acc[mi][ni], 0, 0, 0);
      }
    __syncthreads();
  }
  #pragma unroll
  for (int mi = 0; mi < 4; ++mi) {
    const int dbase = d0 + wm * 64 + mi * 16 + ((lane >> 4) << 2);
    float bi[4];
    #pragma unroll
    for (int r = 0; r < 4; ++r) bi[r] = bias[dbase + r];
    #pragma unroll
    for (int ni = 0; ni < 4; ++ni) {
      const int nloc = nloc0 + wn * 64 + ni * 16 + (lane & 15);
      H4 hh, ll;
      #pragma unroll
      for (int r = 0; r < 4; ++r) {
        float v = acc[mi][ni][r] + bi[r];
        _Float16 h = (_Float16)v;
        hh.h[r] = h;
        ll.h[r] = (_Float16)(v - (float)h);
        xp[(size_t)(dbase + r) * NC + nloc] = v;
      }
      *(uint2*)&xph[(size_t)nloc * DCODE + dbase] = hh.u;
      *(uint2*)&xpl[(size_t)nloc * DCODE + dbase] = ll.u;
    }
  }
}

// ---- MFMA GEMM2 + argmin ----
__global__ __launch_bounds__(256) void k_gemm2_mfma(
    const _Float16* __restrict__ xph, const _Float16* __restrict__ xpl,
    const _Float16* __restrict__ cbh, const _Float16* __restrict__ cbl,
    const float* __restrict__ cnorm, unsigned long long* __restrict__ packed,
    int n_base, int NC) {
  __shared__ __align__(16) _Float16 As[128 * 64];
  __shared__ __align__(16) _Float16 Bs[128 * 64];
  const int tid = threadIdx.x;
  const int lane = tid & 63, wid = tid >> 6;
  const int wm = wid >> 1, wn = wid & 1;
  const int k0 = blockIdx.x * 128;
  const int nloc0 = blockIdx.y * 128;
  const int r_off = lane >> 3, c16 = lane & 7;

  f32x4 acc[4][4];
  #pragma unroll
  for (int i = 0; i < 4; ++i)
    #pragma unroll
    for (int j = 0; j < 4; ++j) acc[i][j] = (f32x4){0.f, 0.f, 0.f, 0.f};

  for (int kt = 0; kt < DCODE / 32; ++kt) {
    const int dk = kt * 32;
    #pragma unroll
    for (int j = 0; j < 4; ++j) {
      const int r = wid * 32 + j * 8 + r_off;
      const int lg = c16 ^ (r & 7);
      const _Float16* srcA = (lg < 4 ? xph : xpl) + (size_t)(nloc0 + r) * DCODE + dk + (lg & 3) * 8;
      gl_lds16(srcA, As + (size_t)(wid * 32 + j * 8) * 64);
      const _Float16* srcB = (lg < 4 ? cbh : cbl) + (size_t)(k0 + r) * DCODE + dk + (lg & 3) * 8;
      gl_lds16(srcB, Bs + (size_t)(wid * 32 + j * 8) * 64);
    }
    __syncthreads();
    f16x8 a_h[4], a_l[4], b_h[4], b_l[4];
    const int kg = lane >> 4;
    #pragma unroll
    for (int mi = 0; mi < 4; ++mi) {
      const int r = wm * 64 + mi * 16 + (lane & 15);
      a_h[mi] = *(const f16x8*)&As[r * 64 + ((kg)     ^ (r & 7)) * 8];
      a_l[mi] = *(const f16x8*)&As[r * 64 + ((kg + 4) ^ (r & 7)) * 8];
    }
    #pragma unroll
    for (int ni = 0; ni < 4; ++ni) {
      const int r = wn * 64 + ni * 16 + (lane & 15);
      b_h[ni] = *(const f16x8*)&Bs[r * 64 + ((kg)     ^ (r & 7)) * 8];
      b_l[ni] = *(const f16x8*)&Bs[r * 64 + ((kg + 4) ^ (r & 7)) * 8];
    }
    #pragma unroll
    for (int mi = 0; mi < 4; ++mi)
      #pragma unroll
      for (int ni = 0; ni < 4; ++ni) {
        acc[mi][ni] = __builtin_amdgcn_mfma_f32_16x16x32_f16(a_h[mi], b_h[ni], acc[mi][ni], 0, 0, 0);
        acc[mi][ni] = __builtin_amdgcn_mfma_f32_16x16x32_f16(a_h[mi], b_l[ni], acc[mi][ni], 0, 0, 0);
        acc[mi][ni] = __builtin_amdgcn_mfma_f32_16x16x32_f16(a_l[mi], b_h[ni], acc[mi][ni], 0, 0, 0);
      }
    __syncthreads();
  }
  float cn[4];
  int kcol[4];
  #pragma unroll
  for (int ni = 0; ni < 4; ++ni) {
    kcol[ni] = k0 + wn * 64 + ni * 16 + (lane & 15);
    cn[ni] = cnorm[kcol[ni]];
  }
  #pragma unroll
  for (int mi = 0; mi < 4; ++mi) {
    #pragma unroll
    for (int r = 0; r < 4; ++r) {
      float best = 3.4e38f; int bk = 0;
      #pragma unroll
      for (int ni = 0; ni < 4; ++ni) {
        const float v = cn[ni] - 2.0f * acc[mi][ni][r];
        if (v < best) { best = v; bk = kcol[ni]; }
      }
      union { float f; uint32_t u; } cv; cv.f = best;
      uint32_t hi = cv.u ^ ((uint32_t)((int32_t)cv.u >> 31) | 0x80000000u);
      unsigned long long key = ((unsigned long long)hi << 32) | (uint32_t)bk;
      #pragma unroll
      for (int s = 1; s < 16; s <<= 1) {
        unsigned long long o = __shfl_xor(key, s, 64);
        if (o < key) key = o;
      }
      if ((lane & 15) == 0) {
        const int n = n_base + nloc0 + wm * 64 + mi * 16 + ((lane >> 4) << 2) + r;
        atomicMin(&packed[n], key);
      }
    }
  }
}

__global__ __launch_bounds__(256) void k_gather(const float* __restrict__ cb,
                                                const float* __restrict__ xp,
                                                const unsigned long long* __restrict__ packed,
                                                float* __restrict__ out,
                                                double* __restrict__ diffsum,
                                                int n_base, int NC) {
  const int d = blockIdx.y;
  const int nloc = blockIdx.x * 256 + threadIdx.x;
  const int n = n_base + nloc;
  const int b = n >> 10, hw = n & 1023;
  uint32_t idx = (uint32_t)(packed[n] & 0xFFFFFFFFu);
  if (idx > (KCB - 1)) idx = KCB - 1;
  const float q = cb[(size_t)d * KCB + idx];
  const float xv = xp[(size_t)d * NC + nloc];
  const float dd = q - xv;
  out[((size_t)b * DCODE + d) * HWSZ + hw] = q;
  __shared__ float red[256];
  red[threadIdx.x] = dd * dd;
  __syncthreads();
  for (int s = 128; s > 0; s >>= 1) {
    if (threadIdx.x < s) red[threadIdx.x] += red[threadIdx.x + s];
    __syncthreads();
  }
  if (threadIdx.x == 0) atomicAdd(diffsum, (double)red[0]);
}

__global__ void k_final(const unsigned long long* __restrict__ packed,
                        const double* __restrict__ diffsum,
                        float* __restrict__ out) {
  int i = blockIdx.x * 256 + threadIdx.x;
  if (i < NPOS) {
    uint32_t idx = (uint32_t)(packed[i] & 0xFFFFFFFFu);
    if (idx > (KCB - 1)) idx = KCB - 1;
    out[OUT_IDX + i] = (float)idx;
  }
  if (i == 0) out[OUT_DIFF] = (float)(*diffsum / ((double)NPOS * (double)DCODE));
}

extern "C" void kernel_launch(void* const* d_in, const int* in_sizes, int n_in,
                              void* d_out, int out_size, void* d_ws, size_t ws_size,
                              hipStream_t stream) {
  const float* x    = (const float*)d_in[0];
  const float* w    = (const float*)d_in[1];
  const float* bias = (const float*)d_in[2];
  const float* cb   = (const float*)d_in[3];
  float* out = (float*)d_out;
  char* ws = (char*)d_ws;
  unsigned long long* packed = (unsigned long long*)(ws + OFF_PACKED);
  float* cnorm = (float*)(ws + OFF_CNORM);
  double* diffsum = (double*)(ws + OFF_DIFF);
  _Float16* wh  = (_Float16*)(ws + OFF_WH);
  _Float16* wl  = (_Float16*)(ws + OFF_WL);
  _Float16* cbh = (_Float16*)(ws + OFF_CBH);
  _Float16* cbl = (_Float16*)(ws + OFF_CBL);

  // dynamic footprint per chunk = NC*12288 bytes (xp 4096 + xh/xl/xph/xpl 2048 each)
  int NC = 256;
  if      (ws_size >= OFF_DYN + (size_t)4096 * 12288) NC = 4096;
  else if (ws_size >= OFF_DYN + (size_t)2048 * 12288) NC = 2048;
  else if (ws_size >= OFF_DYN + (size_t)1024 * 12288) NC = 1024;
  else if (ws_size >= OFF_DYN + (size_t)512  * 12288) NC = 512;
  const int nchunks = NPOS / NC;
  char* dyn = ws + OFF_DYN;
  float*    xp  = (float*)dyn;
  _Float16* xh  = (_Float16*)(dyn + (size_t)NC * 4096);
  _Float16* xl  = (_Float16*)(dyn + (size_t)NC * 6144);
  _Float16* xph = (_Float16*)(dyn + (size_t)NC * 8192);
  _Float16* xpl = (_Float16*)(dyn + (size_t)NC * 10240);

  k_init<<<64, 256, 0, stream>>>(packed, diffsum);
  k_prep_w<<<DCODE, 256, 0, stream>>>(w, wh, wl);
  k_prep_cb<<<dim3(KCB / 64, DCODE / 64), 256, 0, stream>>>(cb, cbh, cbl);
  k_cnorm2<<<KCB, 256, 0, stream>>>(cbh, cbl, cnorm);
  for (int c = 0; c < nchunks; ++c) {
    const int n_base = c * NC;
    k_prep_x<<<dim3(NC / 64, CIN / 64), 256, 0, stream>>>(x, xh, xl, n_base);
    k_gemm1_mfma<<<dim3(NC / 128, DCODE / 128), 256, 0, stream>>>(wh, wl, xh, xl, bias, xp, xph, xpl, NC);
    k_gemm2_mfma<<<dim3(KCB / 128, NC / 128), 256, 0, stream>>>(xph, xpl, cbh, cbl, cnorm, packed, n_base, NC);
    k_gather<<<dim3(NC / 256, DCODE), 256, 0, stream>>>(cb, xp, packed, out, diffsum, n_base, NC);
  }
  k_final<<<64, 256, 0, stream>>>(packed, diffsum, out);
}

// Round 5
// 406.639 us; speedup vs baseline: 4.2071x; 3.1212x over previous
//
#include <hip/hip_runtime.h>
#include <stdint.h>

// Problem constants
#define BATCH 16
#define CIN   1024
#define HWSZ  1024
#define NPOS  16384
#define DCODE 1024
#define KCB   2048

// d_out FLOAT32: [0,16777216) quant (B,D,H,W); [16777216] diff; [16777217,+16384) indices
#define OUT_QUANT 0
#define OUT_DIFF  16777216
#define OUT_IDX   16777217

// ws layout (bytes)
#define OFF_PACKED 0u            // 16384 u64 = 128 KB
#define OFF_CNORM  131072u       // 2048 f32
#define OFF_DIFF   139264u       // 1 double
#define OFF_WH     262144u       // [d][c] f16, 2 MB
#define OFF_WL     2359296u
#define OFF_CBH    4456448u      // [k][d] f16, 4 MB
#define OFF_CBL    8650752u
#define OFF_DYN    12845056u
// dynamic per chunk: xh [NC][C] | xl | xph [NC][D] | xpl  => 4 * NC*2048 = NC*8192 bytes

typedef _Float16 f16x8 __attribute__((ext_vector_type(8)));
typedef float f32x4 __attribute__((ext_vector_type(4)));
union H4 { _Float16 h[4]; uint2 u; };
union H8 { _Float16 h[8]; uint4 u; };

__device__ __forceinline__ void gl_lds16(const void* g, void* l) {
  __builtin_amdgcn_global_load_lds(
      (const __attribute__((address_space(1))) uint32_t*)g,
      (__attribute__((address_space(3))) uint32_t*)l, 16, 0, 0);
}

__global__ void k_init(unsigned long long* __restrict__ packed, double* __restrict__ diffsum) {
  int i = blockIdx.x * 256 + threadIdx.x;
  if (i < NPOS) packed[i] = 0xFFFFFFFFFFFFFFFFull;
  if (i == 0) *diffsum = 0.0;
}

__global__ __launch_bounds__(256) void k_prep_w(const float* __restrict__ w,
                                                _Float16* __restrict__ wh, _Float16* __restrict__ wl) {
  const int d = blockIdx.x;
  const int c = threadIdx.x * 4;
  float4 v = *(const float4*)&w[(size_t)d * CIN + c];
  H4 hh, ll;
  float vv[4] = {v.x, v.y, v.z, v.w};
  #pragma unroll
  for (int i = 0; i < 4; ++i) {
    _Float16 h = (_Float16)vv[i];
    hh.h[i] = h;
    ll.h[i] = (_Float16)(vv[i] - (float)h);
  }
  *(uint2*)&wh[(size_t)d * CIN + c] = hh.u;
  *(uint2*)&wl[(size_t)d * CIN + c] = ll.u;
}

// cbh/cbl [k][d] from cb [d][k]: tiled 64x64 transpose + split
__global__ __launch_bounds__(256) void k_prep_cb(const float* __restrict__ cb,
                                                 _Float16* __restrict__ cbh, _Float16* __restrict__ cbl) {
  __shared__ float ts[64][65];
  const int t = threadIdx.x;
  const int k0 = blockIdx.x * 64, d0 = blockIdx.y * 64;
  #pragma unroll
  for (int i = 0; i < 4; ++i) {
    const int r = i * 16 + (t >> 4);          // d-local
    float4 v = *(const float4*)&cb[(size_t)(d0 + r) * KCB + k0 + (t & 15) * 4];
    ts[r][(t & 15) * 4 + 0] = v.x; ts[r][(t & 15) * 4 + 1] = v.y;
    ts[r][(t & 15) * 4 + 2] = v.z; ts[r][(t & 15) * 4 + 3] = v.w;
  }
  __syncthreads();
  const int j = t >> 2;          // k-local
  const int q = t & 3;           // d quarter
  H8 hh[2], ll[2];
  #pragma unroll
  for (int e = 0; e < 16; ++e) {
    float xv = ts[q * 16 + e][j];
    _Float16 h = (_Float16)xv;
    hh[e >> 3].h[e & 7] = h;
    ll[e >> 3].h[e & 7] = (_Float16)(xv - (float)h);
  }
  size_t o = (size_t)(k0 + j) * DCODE + d0 + q * 16;
  *(uint4*)&cbh[o] = hh[0].u; *(uint4*)&cbh[o + 8] = hh[1].u;
  *(uint4*)&cbl[o] = ll[0].u; *(uint4*)&cbl[o + 8] = ll[1].u;
}

// xh/xl [nloc][c] from x[b][c][hw] for this chunk
__global__ __launch_bounds__(256) void k_prep_x(const float* __restrict__ x,
                                                _Float16* __restrict__ xh, _Float16* __restrict__ xl,
                                                int n_base) {
  __shared__ float ts[64][65];
  const int t = threadIdx.x;
  const int nt0 = blockIdx.x * 64;
  const int c0 = blockIdx.y * 64;
  const int ng = n_base + nt0;
  const int b = ng >> 10, hw0 = ng & 1023;
  #pragma unroll
  for (int i = 0; i < 4; ++i) {
    const int r = i * 16 + (t >> 4);          // c-local
    float4 v = *(const float4*)&x[((size_t)b * CIN + c0 + r) * HWSZ + hw0 + (t & 15) * 4];
    ts[r][(t & 15) * 4 + 0] = v.x; ts[r][(t & 15) * 4 + 1] = v.y;
    ts[r][(t & 15) * 4 + 2] = v.z; ts[r][(t & 15) * 4 + 3] = v.w;
  }
  __syncthreads();
  const int j = t >> 2;          // n-local
  const int q = t & 3;           // c quarter
  H8 hh[2], ll[2];
  #pragma unroll
  for (int e = 0; e < 16; ++e) {
    float xv = ts[q * 16 + e][j];
    _Float16 h = (_Float16)xv;
    hh[e >> 3].h[e & 7] = h;
    ll[e >> 3].h[e & 7] = (_Float16)(xv - (float)h);
  }
  size_t o = (size_t)(nt0 + j) * CIN + c0 + q * 16;
  *(uint4*)&xh[o] = hh[0].u; *(uint4*)&xh[o + 8] = hh[1].u;
  *(uint4*)&xl[o] = ll[0].u; *(uint4*)&xl[o + 8] = ll[1].u;
}

__global__ __launch_bounds__(256) void k_cnorm2(const _Float16* __restrict__ cbh,
                                                const _Float16* __restrict__ cbl,
                                                float* __restrict__ cnorm) {
  __shared__ double rd[256];
  const int k = blockIdx.x;
  const int t = threadIdx.x;
  H4 hh, ll;
  hh.u = *(const uint2*)&cbh[(size_t)k * DCODE + t * 4];
  ll.u = *(const uint2*)&cbl[(size_t)k * DCODE + t * 4];
  double s = 0.0;
  #pragma unroll
  for (int i = 0; i < 4; ++i) {
    float v = (float)hh.h[i] + (float)ll.h[i];
    s += (double)v * v;
  }
  rd[t] = s;
  __syncthreads();
  for (int st = 128; st > 0; st >>= 1) {
    if (t < st) rd[t] += rd[t + st];
    __syncthreads();
  }
  if (t == 0) cnorm[k] = (float)rd[0];
}

// ---- MFMA GEMM1: C[d][n] = W[d][c] x X^T[c][n] + bias; outputs xph/xpl [n][d] only ----
__global__ __launch_bounds__(256) void k_gemm1_mfma(
    const _Float16* __restrict__ wh, const _Float16* __restrict__ wl,
    const _Float16* __restrict__ xh, const _Float16* __restrict__ xl,
    const float* __restrict__ bias,
    _Float16* __restrict__ xph, _Float16* __restrict__ xpl, int NC) {
  __shared__ __align__(16) _Float16 As[128 * 64];
  __shared__ __align__(16) _Float16 Bs[128 * 64];
  const int tid = threadIdx.x;
  const int lane = tid & 63, wid = tid >> 6;
  const int wm = wid >> 1, wn = wid & 1;
  const int nloc0 = blockIdx.x * 128;
  const int d0 = blockIdx.y * 128;
  const int r_off = lane >> 3, c16 = lane & 7;

  f32x4 acc[4][4];
  #pragma unroll
  for (int i = 0; i < 4; ++i)
    #pragma unroll
    for (int j = 0; j < 4; ++j) acc[i][j] = (f32x4){0.f, 0.f, 0.f, 0.f};

  for (int kt = 0; kt < CIN / 32; ++kt) {
    const int dk = kt * 32;
    #pragma unroll
    for (int j = 0; j < 4; ++j) {
      const int r = wid * 32 + j * 8 + r_off;
      const int lg = c16 ^ (r & 7);
      const _Float16* srcA = (lg < 4 ? wh : wl) + (size_t)(d0 + r) * CIN + dk + (lg & 3) * 8;
      gl_lds16(srcA, As + (size_t)(wid * 32 + j * 8) * 64);
      const _Float16* srcB = (lg < 4 ? xh : xl) + (size_t)(nloc0 + r) * CIN + dk + (lg & 3) * 8;
      gl_lds16(srcB, Bs + (size_t)(wid * 32 + j * 8) * 64);
    }
    __syncthreads();
    f16x8 a_h[4], a_l[4], b_h[4], b_l[4];
    const int kg = lane >> 4;
    #pragma unroll
    for (int mi = 0; mi < 4; ++mi) {
      const int r = wm * 64 + mi * 16 + (lane & 15);
      a_h[mi] = *(const f16x8*)&As[r * 64 + ((kg)     ^ (r & 7)) * 8];
      a_l[mi] = *(const f16x8*)&As[r * 64 + ((kg + 4) ^ (r & 7)) * 8];
    }
    #pragma unroll
    for (int ni = 0; ni < 4; ++ni) {
      const int r = wn * 64 + ni * 16 + (lane & 15);
      b_h[ni] = *(const f16x8*)&Bs[r * 64 + ((kg)     ^ (r & 7)) * 8];
      b_l[ni] = *(const f16x8*)&Bs[r * 64 + ((kg + 4) ^ (r & 7)) * 8];
    }
    #pragma unroll
    for (int mi = 0; mi < 4; ++mi)
      #pragma unroll
      for (int ni = 0; ni < 4; ++ni) {
        acc[mi][ni] = __builtin_amdgcn_mfma_f32_16x16x32_f16(a_h[mi], b_h[ni], acc[mi][ni], 0, 0, 0);
        acc[mi][ni] = __builtin_amdgcn_mfma_f32_16x16x32_f16(a_h[mi], b_l[ni], acc[mi][ni], 0, 0, 0);
        acc[mi][ni] = __builtin_amdgcn_mfma_f32_16x16x32_f16(a_l[mi], b_h[ni], acc[mi][ni], 0, 0, 0);
      }
    __syncthreads();
  }
  #pragma unroll
  for (int mi = 0; mi < 4; ++mi) {
    const int dbase = d0 + wm * 64 + mi * 16 + ((lane >> 4) << 2);
    float bi[4];
    #pragma unroll
    for (int r = 0; r < 4; ++r) bi[r] = bias[dbase + r];
    #pragma unroll
    for (int ni = 0; ni < 4; ++ni) {
      const int nloc = nloc0 + wn * 64 + ni * 16 + (lane & 15);
      H4 hh, ll;
      #pragma unroll
      for (int r = 0; r < 4; ++r) {
        float v = acc[mi][ni][r] + bi[r];
        _Float16 h = (_Float16)v;
        hh.h[r] = h;
        ll.h[r] = (_Float16)(v - (float)h);
      }
      *(uint2*)&xph[(size_t)nloc * DCODE + dbase] = hh.u;
      *(uint2*)&xpl[(size_t)nloc * DCODE + dbase] = ll.u;
    }
  }
}

// ---- MFMA GEMM2 + argmin ----
__global__ __launch_bounds__(256) void k_gemm2_mfma(
    const _Float16* __restrict__ xph, const _Float16* __restrict__ xpl,
    const _Float16* __restrict__ cbh, const _Float16* __restrict__ cbl,
    const float* __restrict__ cnorm, unsigned long long* __restrict__ packed,
    int n_base, int NC) {
  __shared__ __align__(16) _Float16 As[128 * 64];
  __shared__ __align__(16) _Float16 Bs[128 * 64];
  const int tid = threadIdx.x;
  const int lane = tid & 63, wid = tid >> 6;
  const int wm = wid >> 1, wn = wid & 1;
  const int k0 = blockIdx.x * 128;
  const int nloc0 = blockIdx.y * 128;
  const int r_off = lane >> 3, c16 = lane & 7;

  f32x4 acc[4][4];
  #pragma unroll
  for (int i = 0; i < 4; ++i)
    #pragma unroll
    for (int j = 0; j < 4; ++j) acc[i][j] = (f32x4){0.f, 0.f, 0.f, 0.f};

  for (int kt = 0; kt < DCODE / 32; ++kt) {
    const int dk = kt * 32;
    #pragma unroll
    for (int j = 0; j < 4; ++j) {
      const int r = wid * 32 + j * 8 + r_off;
      const int lg = c16 ^ (r & 7);
      const _Float16* srcA = (lg < 4 ? xph : xpl) + (size_t)(nloc0 + r) * DCODE + dk + (lg & 3) * 8;
      gl_lds16(srcA, As + (size_t)(wid * 32 + j * 8) * 64);
      const _Float16* srcB = (lg < 4 ? cbh : cbl) + (size_t)(k0 + r) * DCODE + dk + (lg & 3) * 8;
      gl_lds16(srcB, Bs + (size_t)(wid * 32 + j * 8) * 64);
    }
    __syncthreads();
    f16x8 a_h[4], a_l[4], b_h[4], b_l[4];
    const int kg = lane >> 4;
    #pragma unroll
    for (int mi = 0; mi < 4; ++mi) {
      const int r = wm * 64 + mi * 16 + (lane & 15);
      a_h[mi] = *(const f16x8*)&As[r * 64 + ((kg)     ^ (r & 7)) * 8];
      a_l[mi] = *(const f16x8*)&As[r * 64 + ((kg + 4) ^ (r & 7)) * 8];
    }
    #pragma unroll
    for (int ni = 0; ni < 4; ++ni) {
      const int r = wn * 64 + ni * 16 + (lane & 15);
      b_h[ni] = *(const f16x8*)&Bs[r * 64 + ((kg)     ^ (r & 7)) * 8];
      b_l[ni] = *(const f16x8*)&Bs[r * 64 + ((kg + 4) ^ (r & 7)) * 8];
    }
    #pragma unroll
    for (int mi = 0; mi < 4; ++mi)
      #pragma unroll
      for (int ni = 0; ni < 4; ++ni) {
        acc[mi][ni] = __builtin_amdgcn_mfma_f32_16x16x32_f16(a_h[mi], b_h[ni], acc[mi][ni], 0, 0, 0);
        acc[mi][ni] = __builtin_amdgcn_mfma_f32_16x16x32_f16(a_h[mi], b_l[ni], acc[mi][ni], 0, 0, 0);
        acc[mi][ni] = __builtin_amdgcn_mfma_f32_16x16x32_f16(a_l[mi], b_h[ni], acc[mi][ni], 0, 0, 0);
      }
    __syncthreads();
  }
  float cn[4];
  int kcol[4];
  #pragma unroll
  for (int ni = 0; ni < 4; ++ni) {
    kcol[ni] = k0 + wn * 64 + ni * 16 + (lane & 15);
    cn[ni] = cnorm[kcol[ni]];
  }
  #pragma unroll
  for (int mi = 0; mi < 4; ++mi) {
    #pragma unroll
    for (int r = 0; r < 4; ++r) {
      float best = 3.4e38f; int bk = 0;
      #pragma unroll
      for (int ni = 0; ni < 4; ++ni) {
        const float v = cn[ni] - 2.0f * acc[mi][ni][r];
        if (v < best) { best = v; bk = kcol[ni]; }
      }
      union { float f; uint32_t u; } cv; cv.f = best;
      uint32_t hi = cv.u ^ ((uint32_t)((int32_t)cv.u >> 31) | 0x80000000u);
      unsigned long long key = ((unsigned long long)hi << 32) | (uint32_t)bk;
      #pragma unroll
      for (int s = 1; s < 16; s <<= 1) {
        unsigned long long o = __shfl_xor(key, s, 64);
        if (o < key) key = o;
      }
      if ((lane & 15) == 0) {
        const int n = n_base + nloc0 + wm * 64 + mi * 16 + ((lane >> 4) << 2) + r;
        atomicMin(&packed[n], key);
      }
    }
  }
}

// ---- Coalesced gather via transposed codebook rows + LDS tile transpose ----
// Block: 64 n's x all 1024 d (16 tiles of 64). quant = cbh+cbl row; xp = xph+xpl.
__global__ __launch_bounds__(256) void k_gather2(
    const _Float16* __restrict__ cbh, const _Float16* __restrict__ cbl,
    const _Float16* __restrict__ xph, const _Float16* __restrict__ xpl,
    const unsigned long long* __restrict__ packed,
    float* __restrict__ out, double* __restrict__ diffsum,
    int n_base, int NC) {
  __shared__ float tile[64][65];
  __shared__ uint32_t sidx[64];
  __shared__ float red[256];
  const int t = threadIdx.x;
  const int n0 = blockIdx.x * 64;          // chunk-local, 64 n's stay within one b
  const int ng = n_base + n0;
  const int b = ng >> 10, hw0 = ng & 1023;
  if (t < 64) {
    uint32_t idx = (uint32_t)(packed[ng + t] & 0xFFFFFFFFu);
    if (idx > (KCB - 1)) idx = KCB - 1;
    sidx[t] = idx;
  }
  const int rrow = t >> 3, rcol = (t & 7) * 8;   // load: 32 rows/pass, 8x16B chunks
  const int wd = t >> 4, whw = (t & 15) * 4;     // write: 16 d x 64 hw per pass
  float local = 0.f;
  for (int d0 = 0; d0 < DCODE; d0 += 64) {
    __syncthreads();   // sidx ready (iter 0); tile read (prev iter) done
    #pragma unroll
    for (int p = 0; p < 2; ++p) {
      const int nl = p * 32 + rrow;
      const uint32_t idx = sidx[nl];
      H8 hh, ll, ph, pl;
      hh.u = *(const uint4*)&cbh[(size_t)idx * DCODE + d0 + rcol];
      ll.u = *(const uint4*)&cbl[(size_t)idx * DCODE + d0 + rcol];
      ph.u = *(const uint4*)&xph[(size_t)(n0 + nl) * DCODE + d0 + rcol];
      pl.u = *(const uint4*)&xpl[(size_t)(n0 + nl) * DCODE + d0 + rcol];
      #pragma unroll
      for (int j = 0; j < 8; ++j) {
        const float q = (float)hh.h[j] + (float)ll.h[j];
        const float xv = (float)ph.h[j] + (float)pl.h[j];
        const float dd = q - xv;
        local += dd * dd;
        tile[nl][rcol + j] = q;
      }
    }
    __syncthreads();
    #pragma unroll
    for (int i = 0; i < 4; ++i) {
      const int dl = i * 16 + wd;
      float4 v;
      v.x = tile[whw + 0][dl]; v.y = tile[whw + 1][dl];
      v.z = tile[whw + 2][dl]; v.w = tile[whw + 3][dl];
      *(float4*)&out[((size_t)b * DCODE + d0 + dl) * HWSZ + hw0 + whw] = v;
    }
  }
  red[t] = local;
  __syncthreads();
  for (int s = 128; s > 0; s >>= 1) {
    if (t < s) red[t] += red[t + s];
    __syncthreads();
  }
  if (t == 0) atomicAdd(diffsum, (double)red[0]);
}

__global__ void k_final(const unsigned long long* __restrict__ packed,
                        const double* __restrict__ diffsum,
                        float* __restrict__ out) {
  int i = blockIdx.x * 256 + threadIdx.x;
  if (i < NPOS) {
    uint32_t idx = (uint32_t)(packed[i] & 0xFFFFFFFFu);
    if (idx > (KCB - 1)) idx = KCB - 1;
    out[OUT_IDX + i] = (float)idx;
  }
  if (i == 0) out[OUT_DIFF] = (float)(*diffsum / ((double)NPOS * (double)DCODE));
}

extern "C" void kernel_launch(void* const* d_in, const int* in_sizes, int n_in,
                              void* d_out, int out_size, void* d_ws, size_t ws_size,
                              hipStream_t stream) {
  const float* x    = (const float*)d_in[0];
  const float* w    = (const float*)d_in[1];
  const float* bias = (const float*)d_in[2];
  const float* cb   = (const float*)d_in[3];
  float* out = (float*)d_out;
  char* ws = (char*)d_ws;
  unsigned long long* packed = (unsigned long long*)(ws + OFF_PACKED);
  float* cnorm = (float*)(ws + OFF_CNORM);
  double* diffsum = (double*)(ws + OFF_DIFF);
  _Float16* wh  = (_Float16*)(ws + OFF_WH);
  _Float16* wl  = (_Float16*)(ws + OFF_WL);
  _Float16* cbh = (_Float16*)(ws + OFF_CBH);
  _Float16* cbl = (_Float16*)(ws + OFF_CBL);

  // dynamic footprint per chunk = NC*8192 bytes (xh/xl/xph/xpl, NC*2048 each)
  int NC = 256;
  if      (ws_size >= OFF_DYN + (size_t)16384 * 8192) NC = 16384;
  else if (ws_size >= OFF_DYN + (size_t)8192  * 8192) NC = 8192;
  else if (ws_size >= OFF_DYN + (size_t)4096  * 8192) NC = 4096;
  else if (ws_size >= OFF_DYN + (size_t)2048  * 8192) NC = 2048;
  else if (ws_size >= OFF_DYN + (size_t)1024  * 8192) NC = 1024;
  else if (ws_size >= OFF_DYN + (size_t)512   * 8192) NC = 512;
  const int nchunks = NPOS / NC;
  char* dyn = ws + OFF_DYN;
  _Float16* xh  = (_Float16*)dyn;
  _Float16* xl  = (_Float16*)(dyn + (size_t)NC * 2048);
  _Float16* xph = (_Float16*)(dyn + (size_t)NC * 4096);
  _Float16* xpl = (_Float16*)(dyn + (size_t)NC * 6144);

  k_init<<<64, 256, 0, stream>>>(packed, diffsum);
  k_prep_w<<<DCODE, 256, 0, stream>>>(w, wh, wl);
  k_prep_cb<<<dim3(KCB / 64, DCODE / 64), 256, 0, stream>>>(cb, cbh, cbl);
  k_cnorm2<<<KCB, 256, 0, stream>>>(cbh, cbl, cnorm);
  for (int c = 0; c < nchunks; ++c) {
    const int n_base = c * NC;
    k_prep_x<<<dim3(NC / 64, CIN / 64), 256, 0, stream>>>(x, xh, xl, n_base);
    k_gemm1_mfma<<<dim3(NC / 128, DCODE / 128), 256, 0, stream>>>(wh, wl, xh, xl, bias, xph, xpl, NC);
    k_gemm2_mfma<<<dim3(KCB / 128, NC / 128), 256, 0, stream>>>(xph, xpl, cbh, cbl, cnorm, packed, n_base, NC);
    k_gather2<<<dim3(NC / 64), 256, 0, stream>>>(cbh, cbl, xph, xpl, packed, out, diffsum, n_base, NC);
  }
  k_final<<<64, 256, 0, stream>>>(packed, diffsum, out);
}